// Round 5
// baseline (210.561 us; speedup 1.0000x reference)
//
#include <hip/hip_runtime.h>

#define Bn 4
#define Cn 256
#define HWn 4096
#define CPn 64
#define MP 640   // CW rows padded 576 -> 640 (5 x 128)

typedef unsigned short u16;
typedef unsigned int u32;

using short8  = __attribute__((ext_vector_type(8))) short;
using floatx4 = __attribute__((ext_vector_type(4))) float;

static __device__ __forceinline__ u16 f2bf(float f) {
    union { float f; u32 u; } v; v.f = f;
    u32 r = (v.u + 0x7FFFu + ((v.u >> 16) & 1u)) >> 16;
    return (u16)r;
}

// async global -> LDS, 16 B per lane. LDS dest = wave-uniform base + lane*16.
static __device__ __forceinline__ void gld16(const u16* g, u16* l) {
    __builtin_amdgcn_global_load_lds(
        (const __attribute__((address_space(1))) u32*)g,
        (__attribute__((address_space(3))) u32*)l, 16, 0, 0);
}

// Pane layout: one pane = one MFMA fragment set = 64 lanes x 16B = 1 KB.
// pane p covers rows [(p>>1)*16, +16) x k-chunk (p&1) (32 wide).
// Lane l holds (row = l&15, k = (p&1)*32 + (l>>4)*8 .. +7).
// Compute-side fragment read = base + lane*16B: contiguous, conflict-free.

// ---------------------------------------------------------------------------
// K1: fp32 (C x HW) -> bf16 (HW x C) transpose per (s,b).  xT[s][b][hw][c]
// ---------------------------------------------------------------------------
__global__ __launch_bounds__(256) void convert_transpose(
    const float* __restrict__ Tt, const float* __restrict__ Bt, const float* __restrict__ Mt,
    u16* __restrict__ xT)
{
    const int s  = blockIdx.z, b = blockIdx.y;
    const int ct = blockIdx.x & 3, hwt = blockIdx.x >> 2;
    const int c0 = ct * 64, hw0 = hwt * 64;
    const float* X = (s == 0 ? Tt : (s == 1 ? Bt : Mt)) + (size_t)b * Cn * HWn;

    __shared__ u16 T[64][72];
    const int t = threadIdx.x;
    const int cl = t >> 2, q = t & 3;

    const float* src = X + (size_t)(c0 + cl) * HWn + hw0 + q * 16;
    #pragma unroll
    for (int u = 0; u < 4; ++u) {
        const float4 v = *(const float4*)(src + u * 4);
        T[cl][q * 16 + u * 4 + 0] = f2bf(v.x);
        T[cl][q * 16 + u * 4 + 1] = f2bf(v.y);
        T[cl][q * 16 + u * 4 + 2] = f2bf(v.z);
        T[cl][q * 16 + u * 4 + 3] = f2bf(v.w);
    }
    __syncthreads();

    const int wl = t >> 2;
    u16* dst = xT + ((size_t)((s * Bn + b) * HWn) + hw0 + wl) * Cn + c0 + q * 16;
    #pragma unroll
    for (int u = 0; u < 2; ++u) {
        u32 w0 = (u32)T[q * 16 + u * 8 + 0][wl] | ((u32)T[q * 16 + u * 8 + 1][wl] << 16);
        u32 w1 = (u32)T[q * 16 + u * 8 + 2][wl] | ((u32)T[q * 16 + u * 8 + 3][wl] << 16);
        u32 w2 = (u32)T[q * 16 + u * 8 + 4][wl] | ((u32)T[q * 16 + u * 8 + 5][wl] << 16);
        u32 w3 = (u32)T[q * 16 + u * 8 + 6][wl] | ((u32)T[q * 16 + u * 8 + 7][wl] << 16);
        uint4 pk = {w0, w1, w2, w3};
        *(uint4*)(dst + u * 8) = pk;
    }
}

// ---------------------------------------------------------------------------
// K2: compose CWp[s] (640 x 256) bf16 = stack of Wred[idx] @ Wqkv[3s+tt].
// rows [tt*192 + m*64 + r], idx = (tt==1)? 3s+m : 3m+s.  rows 576..639 = 0 (memset).
// ---------------------------------------------------------------------------
__global__ __launch_bounds__(256) void compose_red(
    const float* __restrict__ Wqkv, const float* __restrict__ Wred,
    u16* __restrict__ CWp)
{
    const int s  = blockIdx.z;
    const int tt = blockIdx.y / 3, m3 = blockIdx.y % 3;
    const int c0 = blockIdx.x * 64;
    const int idx = (tt == 1) ? (3 * s + m3) : (3 * m3 + s);

    const float* A = Wred + (size_t)idx * CPn * Cn;          // 64 x 256 (r,e)
    const float* Bm = Wqkv + (size_t)(3 * s + tt) * Cn * Cn; // 256 x 256 (e,c)

    __shared__ float As[16][64];
    __shared__ float Bs[16][64];
    const int t = threadIdx.x;
    const int ty = t >> 4, tx = t & 15;
    float acc[4][4] = {};

    for (int k0 = 0; k0 < Cn; k0 += 16) {
        {
            const int r = t >> 2, eq = (t & 3) * 4;
            const float4 a = *(const float4*)(A + (size_t)r * Cn + k0 + eq);
            As[eq + 0][r] = a.x; As[eq + 1][r] = a.y; As[eq + 2][r] = a.z; As[eq + 3][r] = a.w;
        }
        {
            const int r = t >> 4, cq = (t & 15) * 4;
            *(float4*)(&Bs[r][cq]) = *(const float4*)(Bm + (size_t)(k0 + r) * Cn + c0 + cq);
        }
        __syncthreads();
        #pragma unroll
        for (int k = 0; k < 16; ++k) {
            const float4 a4 = *(const float4*)(&As[k][ty * 4]);
            const float4 b4 = *(const float4*)(&Bs[k][tx * 4]);
            const float a[4] = {a4.x, a4.y, a4.z, a4.w};
            const float bb[4] = {b4.x, b4.y, b4.z, b4.w};
            #pragma unroll
            for (int i = 0; i < 4; ++i)
                #pragma unroll
                for (int j = 0; j < 4; ++j)
                    acc[i][j] = fmaf(a[i], bb[j], acc[i][j]);
        }
        __syncthreads();
    }

    u16* out = CWp + (size_t)s * MP * Cn;
    #pragma unroll
    for (int i = 0; i < 4; ++i) {
        const int row = tt * 192 + m3 * 64 + ty * 4 + i;
        unsigned long long pk =
            (unsigned long long)f2bf(acc[i][0]) |
            ((unsigned long long)f2bf(acc[i][1]) << 16) |
            ((unsigned long long)f2bf(acc[i][2]) << 32) |
            ((unsigned long long)f2bf(acc[i][3]) << 48);
        *(unsigned long long*)(out + (size_t)row * Cn + c0 + tx * 4) = pk;
    }
}

// ---------------------------------------------------------------------------
// K3: per s: CWp (640 x 256) @ xT^T (256 x 16384).  Tile 128(M) x 256(N), BK=64.
// Pane-ordered LDS, global_load_lds staging.  ATOMIC-FREE epilogue: per-block
// relu+pool partials -> Psum/Pmax[s][R][nt]  (reduced over nt in attn_small).
// ---------------------------------------------------------------------------
__global__ __launch_bounds__(256) void redpool_mfma(
    const u16* __restrict__ xT, const u16* __restrict__ CWp,
    float* __restrict__ Psum, float* __restrict__ Pmax)
{
    const int s  = blockIdx.z;
    const int mt = blockIdx.x >> 6, nt = blockIdx.x & 63;
    const int m0 = mt * 128, n0 = nt * 256;           // n = b*4096 + hw

    const u16* Ap = CWp + (size_t)s * MP * Cn;
    const u16* Bp = xT + (size_t)s * Bn * HWn * Cn;

    __shared__ __align__(16) u16 As[16 * 512];   // 16 panes (128 rows x 64 k)
    __shared__ __align__(16) u16 Bs[32 * 512];   // 32 panes (256 rows x 64 k)
    __shared__ float Lsum[2][128];
    __shared__ float Lmax[2][128];

    const int t = threadIdx.x;
    const int w = t >> 6, lane = t & 63;
    const int l15 = lane & 15, q = lane >> 4;
    const int rb = (w >> 1) * 64;

    floatx4 acc[4][8] = {};

    for (int k0 = 0; k0 < Cn; k0 += 64) {
        const u16* Asrc = Ap + (size_t)m0 * Cn + k0 + (size_t)l15 * Cn + q * 8;
        const u16* Bsrc = Bp + (size_t)n0 * Cn + k0 + (size_t)l15 * Cn + q * 8;
        #pragma unroll
        for (int pi = 0; pi < 4; ++pi) {          // A panes: 4 per wave
            const int p = w * 4 + pi;
            gld16(Asrc + (size_t)((p >> 1) * 16) * Cn + (p & 1) * 32, &As[p * 512]);
        }
        #pragma unroll
        for (int pi = 0; pi < 8; ++pi) {          // B panes: 8 per wave
            const int p = w * 8 + pi;
            gld16(Bsrc + (size_t)((p >> 1) * 16) * Cn + (p & 1) * 32, &Bs[p * 512]);
        }
        __syncthreads();
        #pragma unroll
        for (int kk = 0; kk < 2; ++kk) {
            short8 af[4], bf[8];
            #pragma unroll
            for (int i = 0; i < 4; ++i)
                af[i] = *(const short8*)&As[((((w >> 1) * 4 + i) << 1) + kk) * 512 + lane * 8];
            #pragma unroll
            for (int j = 0; j < 8; ++j)
                bf[j] = *(const short8*)&Bs[((((w & 1) * 8 + j) << 1) + kk) * 512 + lane * 8];
            #pragma unroll
            for (int i = 0; i < 4; ++i)
                #pragma unroll
                for (int j = 0; j < 8; ++j)
                    acc[i][j] = __builtin_amdgcn_mfma_f32_16x16x32_bf16(af[i], bf[j], acc[i][j], 0, 0, 0);
        }
        __syncthreads();
    }

    // relu + pool over this block's 256 cols (all same b); no atomics.
    const int wi = w & 1;
    #pragma unroll
    for (int i = 0; i < 4; ++i) {
        #pragma unroll
        for (int r = 0; r < 4; ++r) {
            float rs = 0.f, rm = 0.f;
            #pragma unroll
            for (int j = 0; j < 8; ++j) {
                const float v = fmaxf(acc[i][j][r], 0.f);
                rs += v; rm = fmaxf(rm, v);
            }
            #pragma unroll
            for (int off = 1; off < 16; off <<= 1) {
                rs += __shfl_xor(rs, off);
                rm = fmaxf(rm, __shfl_xor(rm, off));
            }
            if (l15 == 0) {
                const int lr = rb + 16 * i + q * 4 + r;
                Lsum[wi][lr] = rs;
                Lmax[wi][lr] = rm;
            }
        }
    }
    __syncthreads();
    if (t < 128) {
        const int R = m0 + t;
        Psum[((size_t)s * MP + R) * 64 + nt] = Lsum[0][t] + Lsum[1][t];
        Pmax[((size_t)s * MP + R) * 64 + nt] = fmaxf(Lmax[0][t], Lmax[1][t]);
    }
}

// ---------------------------------------------------------------------------
// K4: tiny attention per (idx,b): reduce partials -> f,g,h -> softmax -> vout
// -> o = sigmoid(W_rec vout) -> coefA/coefK accumulation (fp32)
// ---------------------------------------------------------------------------
__global__ __launch_bounds__(256) void attn_small(
    const float* __restrict__ Psum, const float* __restrict__ Pmax,
    const float* __restrict__ Wrec,
    float* __restrict__ coefA, float* __restrict__ coefK)
{
    const int idx = blockIdx.x / Bn;
    const int bb  = blockIdx.x % Bn;
    __shared__ float ff[CPn], gg[CPn], hh[CPn], vout[CPn];
    const int t = threadIdx.x;

    if (t < CPn) {
        float v[3];
        #pragma unroll
        for (int tt = 0; tt < 3; ++tt) {
            const int s_ = (tt == 1) ? idx / 3 : idx % 3;
            const int m3 = (tt == 1) ? idx % 3 : idx / 3;
            const int R  = tt * 192 + m3 * 64 + t;
            const size_t base = ((size_t)s_ * MP + R) * 64 + bb * 16;
            float sm = 0.f, mx = 0.f;
            #pragma unroll
            for (int u = 0; u < 16; ++u) {
                sm += Psum[base + u];
                mx = fmaxf(mx, Pmax[base + u]);
            }
            v[tt] = sm * (1.0f / HWn) + mx;
        }
        gg[t] = v[0];   // Q-pool
        ff[t] = v[1];   // K-pool
        hh[t] = v[2];   // V-pool
    }
    __syncthreads();

    if (t < CPn) {
        const float gj = gg[t];
        float mx = -1e30f;
        for (int i = 0; i < CPn; ++i) mx = fmaxf(mx, ff[i] * gj);
        float den = 0.f, num = 0.f;
        for (int i = 0; i < CPn; ++i) {
            const float e = expf(ff[i] * gj - mx);
            den += e;
            num += hh[i] * e;
        }
        vout[t] = num / den;
    }
    __syncthreads();

    {
        const float* wr = Wrec + ((size_t)idx * Cn + t) * CPn;
        float a = 0.f;
        for (int e = 0; e < CPn; ++e) a += vout[e] * wr[e];
        const float o = 1.0f / (1.0f + expf(-a));
        const int sj = idx % 3;
        const int si = idx / 3;
        atomicAdd(coefA + (sj * Bn + bb) * Cn + t, o);
        atomicAdd(coefK + (si * Bn + bb) * Cn + t, o);
    }
}

// ---------------------------------------------------------------------------
// K5: build composed output matrix Mm[b][m][s*256+c] bf16
// ---------------------------------------------------------------------------
__global__ __launch_bounds__(256) void build_M(
    const float* __restrict__ Wqkv,
    const float* __restrict__ coefA, const float* __restrict__ coefK,
    u16* __restrict__ Mm)
{
    const int s = blockIdx.x >> 8, m = blockIdx.x & 255;
    const int b = blockIdx.y;
    const int t = threadIdx.x;
    const float cA = coefA[(s * Bn + b) * Cn + m];
    const float cK = coefK[(s * Bn + b) * Cn + m];
    const float wq = Wqkv[((size_t)(3 * s + 0) * Cn + m) * Cn + t];
    const float wk = Wqkv[((size_t)(3 * s + 1) * Cn + m) * Cn + t];
    const float wv = Wqkv[((size_t)(3 * s + 2) * Cn + m) * Cn + t];
    Mm[((size_t)(b * 256 + m)) * 768 + s * 256 + t] = f2bf(cA * (wq + wv) + cK * wk);
}

// ---------------------------------------------------------------------------
// K6: out[b] (256 x 4096) = Mm[b] (256 x 768) @ xcat[b]^T.
// Tile 128(M) x 64(N), BK=64, 12 K-iters, pane-ordered LDS.  Grid 512.
// ---------------------------------------------------------------------------
__global__ __launch_bounds__(256) void final_mfma(
    const u16* __restrict__ xT, const u16* __restrict__ Mm,
    float* __restrict__ out)
{
    const int b  = blockIdx.y;
    const int mt = blockIdx.x >> 6, nt = blockIdx.x & 63;
    const int m0 = mt * 128, n0 = nt * 64;

    __shared__ __align__(16) u16 As[16 * 512];   // 128 rows x 64 k
    __shared__ __align__(16) u16 Bs[8 * 512];    // 64 rows x 64 k

    const int t = threadIdx.x;
    const int w = t >> 6, lane = t & 63;
    const int l15 = lane & 15, q = lane >> 4;
    const int rb = (w >> 1) * 64, cb = (w & 1) * 32;

    const u16* Apb = Mm + (size_t)(b * 256 + m0) * 768;

    floatx4 acc[4][2] = {};

    for (int k0 = 0; k0 < 768; k0 += 64) {
        const int s = k0 >> 8, c0 = k0 & 255;
        const u16* Asrc = Apb + k0 + (size_t)l15 * 768 + q * 8;
        const u16* Bsrc = xT + ((size_t)((s * Bn + b) * HWn) + n0 + l15) * Cn + c0 + q * 8;
        #pragma unroll
        for (int pi = 0; pi < 4; ++pi) {          // A panes: 4 per wave
            const int p = w * 4 + pi;
            gld16(Asrc + (size_t)((p >> 1) * 16) * 768 + (p & 1) * 32, &As[p * 512]);
        }
        #pragma unroll
        for (int pi = 0; pi < 2; ++pi) {          // B panes: 2 per wave
            const int p = w * 2 + pi;
            gld16(Bsrc + (size_t)((p >> 1) * 16) * Cn + (p & 1) * 32, &Bs[p * 512]);
        }
        __syncthreads();
        #pragma unroll
        for (int kk = 0; kk < 2; ++kk) {
            short8 af[4], bf[2];
            #pragma unroll
            for (int i = 0; i < 4; ++i)
                af[i] = *(const short8*)&As[((((w >> 1) * 4 + i) << 1) + kk) * 512 + lane * 8];
            #pragma unroll
            for (int j = 0; j < 2; ++j)
                bf[j] = *(const short8*)&Bs[((((w & 1) * 2 + j) << 1) + kk) * 512 + lane * 8];
            #pragma unroll
            for (int i = 0; i < 4; ++i)
                #pragma unroll
                for (int j = 0; j < 2; ++j)
                    acc[i][j] = __builtin_amdgcn_mfma_f32_16x16x32_bf16(af[i], bf[j], acc[i][j], 0, 0, 0);
        }
        __syncthreads();
    }

    #pragma unroll
    for (int i = 0; i < 4; ++i)
        #pragma unroll
        for (int j = 0; j < 2; ++j)
            #pragma unroll
            for (int r = 0; r < 4; ++r) {
                const int row = m0 + rb + i * 16 + q * 4 + r;
                const int col = n0 + cb + j * 16 + l15;
                out[((size_t)(b * 256) + row) * HWn + col] = acc[i][j][r];
            }
}

extern "C" void kernel_launch(void* const* d_in, const int* in_sizes, int n_in,
                              void* d_out, int out_size, void* d_ws, size_t ws_size,
                              hipStream_t stream)
{
    const float* Tt   = (const float*)d_in[0];
    const float* Bt   = (const float*)d_in[1];
    const float* Mt   = (const float*)d_in[2];
    const float* Wqkv = (const float*)d_in[3];
    const float* Wred = (const float*)d_in[4];
    const float* Wrec = (const float*)d_in[5];
    float* out = (float*)d_out;

    unsigned char* p = (unsigned char*)d_ws;
    u16* xT = (u16*)p;            p += (size_t)3 * Bn * HWn * Cn * 2;   // 25.2 MB
    u16* Mm = (u16*)p;            p += (size_t)Bn * 256 * 768 * 2;      // 1.57 MB
    float* Psum = (float*)p;      p += (size_t)3 * MP * 64 * 4;         // 491 KB
    float* Pmax = (float*)p;      p += (size_t)3 * MP * 64 * 4;         // 491 KB
    unsigned char* zbase = p;
    u16* CWp = (u16*)p;           p += (size_t)3 * MP * Cn * 2;         // 983 KB (pad rows need 0)
    float* coefA = (float*)p;     p += (size_t)3 * Bn * Cn * 4;
    float* coefK = (float*)p;     p += (size_t)3 * Bn * Cn * 4;
    const size_t zbytes = (size_t)(p - zbase);

    hipMemsetAsync(zbase, 0, zbytes, stream);

    compose_red      <<<dim3(4, 9, 3),    256, 0, stream>>>(Wqkv, Wred, CWp);
    convert_transpose<<<dim3(256, Bn, 3), 256, 0, stream>>>(Tt, Bt, Mt, xT);
    redpool_mfma     <<<dim3(320, 1, 3),  256, 0, stream>>>(xT, CWp, Psum, Pmax);
    attn_small       <<<9 * Bn,           256, 0, stream>>>(Psum, Pmax, Wrec, coefA, coefK);
    build_M          <<<dim3(768, Bn),    256, 0, stream>>>(Wqkv, coefA, coefK, Mm);
    final_mfma       <<<dim3(128, Bn),    256, 0, stream>>>(xT, Mm, out);
}

// Round 6
// 198.007 us; speedup vs baseline: 1.0634x; 1.0634x over previous
//
#include <hip/hip_runtime.h>

#define Bn 4
#define Cn 256
#define HWn 4096
#define CPn 64
#define MP 640   // CW rows padded 576 -> 640 (5 x 128)

typedef unsigned short u16;
typedef unsigned int u32;

using short8  = __attribute__((ext_vector_type(8))) short;
using floatx4 = __attribute__((ext_vector_type(4))) float;

static __device__ __forceinline__ u16 f2bf(float f) {
    union { float f; u32 u; } v; v.f = f;
    u32 r = (v.u + 0x7FFFu + ((v.u >> 16) & 1u)) >> 16;
    return (u16)r;
}

// async global -> LDS, 16 B per lane. LDS dest = wave-uniform base + lane*16.
static __device__ __forceinline__ void gld16(const u16* g, u16* l) {
    __builtin_amdgcn_global_load_lds(
        (const __attribute__((address_space(1))) u32*)g,
        (__attribute__((address_space(3))) u32*)l, 16, 0, 0);
}

// Pane layout: one pane = one MFMA fragment set = 64 lanes x 16B = 1 KB.
// For BK=128 tiles: pane p covers rows [(p>>2)*16, +16) x k-chunk (p&3)*32.
// Lane l holds (row = l&15, k = (p&3)*32 + (l>>4)*8 .. +7).
// Compute-side fragment read = base + lane*16B: contiguous, conflict-free.

// ---------------------------------------------------------------------------
// K1: fp32 (C x HW) -> bf16 (HW x C) transpose per (s,b).  xT[s][b][hw][c]
// ---------------------------------------------------------------------------
__global__ __launch_bounds__(256) void convert_transpose(
    const float* __restrict__ Tt, const float* __restrict__ Bt, const float* __restrict__ Mt,
    u16* __restrict__ xT)
{
    const int s  = blockIdx.z, b = blockIdx.y;
    const int ct = blockIdx.x & 3, hwt = blockIdx.x >> 2;
    const int c0 = ct * 64, hw0 = hwt * 64;
    const float* X = (s == 0 ? Tt : (s == 1 ? Bt : Mt)) + (size_t)b * Cn * HWn;

    __shared__ u16 T[64][72];
    const int t = threadIdx.x;
    const int cl = t >> 2, q = t & 3;

    const float* src = X + (size_t)(c0 + cl) * HWn + hw0 + q * 16;
    #pragma unroll
    for (int u = 0; u < 4; ++u) {
        const float4 v = *(const float4*)(src + u * 4);
        T[cl][q * 16 + u * 4 + 0] = f2bf(v.x);
        T[cl][q * 16 + u * 4 + 1] = f2bf(v.y);
        T[cl][q * 16 + u * 4 + 2] = f2bf(v.z);
        T[cl][q * 16 + u * 4 + 3] = f2bf(v.w);
    }
    __syncthreads();

    const int wl = t >> 2;
    u16* dst = xT + ((size_t)((s * Bn + b) * HWn) + hw0 + wl) * Cn + c0 + q * 16;
    #pragma unroll
    for (int u = 0; u < 2; ++u) {
        u32 w0 = (u32)T[q * 16 + u * 8 + 0][wl] | ((u32)T[q * 16 + u * 8 + 1][wl] << 16);
        u32 w1 = (u32)T[q * 16 + u * 8 + 2][wl] | ((u32)T[q * 16 + u * 8 + 3][wl] << 16);
        u32 w2 = (u32)T[q * 16 + u * 8 + 4][wl] | ((u32)T[q * 16 + u * 8 + 5][wl] << 16);
        u32 w3 = (u32)T[q * 16 + u * 8 + 6][wl] | ((u32)T[q * 16 + u * 8 + 7][wl] << 16);
        uint4 pk = {w0, w1, w2, w3};
        *(uint4*)(dst + u * 8) = pk;
    }
}

// ---------------------------------------------------------------------------
// K2: compose CWp[s] (640 x 256) bf16 = stack of Wred[idx] @ Wqkv[3s+tt].
// rows [tt*192 + m*64 + r], idx = (tt==1)? 3s+m : 3m+s.  rows 576..639 = 0 (memset).
// ---------------------------------------------------------------------------
__global__ __launch_bounds__(256) void compose_red(
    const float* __restrict__ Wqkv, const float* __restrict__ Wred,
    u16* __restrict__ CWp)
{
    const int s  = blockIdx.z;
    const int tt = blockIdx.y / 3, m3 = blockIdx.y % 3;
    const int c0 = blockIdx.x * 64;
    const int idx = (tt == 1) ? (3 * s + m3) : (3 * m3 + s);

    const float* A = Wred + (size_t)idx * CPn * Cn;          // 64 x 256 (r,e)
    const float* Bm = Wqkv + (size_t)(3 * s + tt) * Cn * Cn; // 256 x 256 (e,c)

    __shared__ float As[16][64];
    __shared__ float Bs[16][64];
    const int t = threadIdx.x;
    const int ty = t >> 4, tx = t & 15;
    float acc[4][4] = {};

    for (int k0 = 0; k0 < Cn; k0 += 16) {
        {
            const int r = t >> 2, eq = (t & 3) * 4;
            const float4 a = *(const float4*)(A + (size_t)r * Cn + k0 + eq);
            As[eq + 0][r] = a.x; As[eq + 1][r] = a.y; As[eq + 2][r] = a.z; As[eq + 3][r] = a.w;
        }
        {
            const int r = t >> 4, cq = (t & 15) * 4;
            *(float4*)(&Bs[r][cq]) = *(const float4*)(Bm + (size_t)(k0 + r) * Cn + c0 + cq);
        }
        __syncthreads();
        #pragma unroll
        for (int k = 0; k < 16; ++k) {
            const float4 a4 = *(const float4*)(&As[k][ty * 4]);
            const float4 b4 = *(const float4*)(&Bs[k][tx * 4]);
            const float a[4] = {a4.x, a4.y, a4.z, a4.w};
            const float bb[4] = {b4.x, b4.y, b4.z, b4.w};
            #pragma unroll
            for (int i = 0; i < 4; ++i)
                #pragma unroll
                for (int j = 0; j < 4; ++j)
                    acc[i][j] = fmaf(a[i], bb[j], acc[i][j]);
        }
        __syncthreads();
    }

    u16* out = CWp + (size_t)s * MP * Cn;
    #pragma unroll
    for (int i = 0; i < 4; ++i) {
        const int row = tt * 192 + m3 * 64 + ty * 4 + i;
        unsigned long long pk =
            (unsigned long long)f2bf(acc[i][0]) |
            ((unsigned long long)f2bf(acc[i][1]) << 16) |
            ((unsigned long long)f2bf(acc[i][2]) << 32) |
            ((unsigned long long)f2bf(acc[i][3]) << 48);
        *(unsigned long long*)(out + (size_t)row * Cn + c0 + tx * 4) = pk;
    }
}

// ---------------------------------------------------------------------------
// K3: per s: CWp (640 x 256) @ xT^T (256 x 16384).  Tile 128(M) x 128(N),
// BK=128 -> only 2 K-iterations (2 barrier drains per block).  LDS = 64 KB
// exactly -> 2 blocks/CU.  Pane-ordered LDS, global_load_lds staging.
// Atomic-free epilogue -> Psum/Pmax[s][R][b][chunk] partials.
// ---------------------------------------------------------------------------
__global__ __launch_bounds__(256, 2) void redpool_mfma(
    const u16* __restrict__ xT, const u16* __restrict__ CWp,
    float* __restrict__ Psum, float* __restrict__ Pmax)
{
    const int s  = blockIdx.z;
    const int mt = blockIdx.x >> 7, nt = blockIdx.x & 127;
    const int m0 = mt * 128, n0 = nt * 128;           // n = b*4096 + hw

    const u16* Ap = CWp + (size_t)s * MP * Cn;
    const u16* Bp = xT + (size_t)s * Bn * HWn * Cn;

    __shared__ __align__(16) u16 As[32 * 512];   // 32 panes: 128 rows x 128 k
    __shared__ __align__(16) u16 Bs[32 * 512];   // 32 panes: 128 rows x 128 k

    const int t = threadIdx.x;
    const int w = t >> 6, lane = t & 63;
    const int l15 = lane & 15, q = lane >> 4;
    const int rb = (w >> 1) * 64, cb = (w & 1) * 64;

    floatx4 acc[4][4] = {};

    #pragma unroll
    for (int it = 0; it < 2; ++it) {
        const int k0 = it * 128;
        const u16* Asrc = Ap + (size_t)(m0 + l15) * Cn + k0 + q * 8;
        const u16* Bsrc = Bp + (size_t)(n0 + l15) * Cn + k0 + q * 8;
        #pragma unroll
        for (int pi = 0; pi < 8; ++pi) {          // 8 A panes + 8 B panes per wave
            const int p = w * 8 + pi;
            const size_t roff = (size_t)((p >> 2) * 16);
            gld16(Asrc + roff * Cn + (p & 3) * 32, &As[p * 512]);
            gld16(Bsrc + roff * Cn + (p & 3) * 32, &Bs[p * 512]);
        }
        __syncthreads();
        #pragma unroll
        for (int kk = 0; kk < 4; ++kk) {
            short8 af[4], bf[4];
            #pragma unroll
            for (int i = 0; i < 4; ++i)
                af[i] = *(const short8*)&As[((((w >> 1) * 4 + i) << 2) + kk) * 512 + lane * 8];
            #pragma unroll
            for (int j = 0; j < 4; ++j)
                bf[j] = *(const short8*)&Bs[((((w & 1) * 4 + j) << 2) + kk) * 512 + lane * 8];
            #pragma unroll
            for (int i = 0; i < 4; ++i)
                #pragma unroll
                for (int j = 0; j < 4; ++j)
                    acc[i][j] = __builtin_amdgcn_mfma_f32_16x16x32_bf16(af[i], bf[j], acc[i][j], 0, 0, 0);
        }
        __syncthreads();
    }

    // relu + pool over this block's 128 cols (all same b); no atomics.
    // Overlay the tiny combine arrays onto As (all fragment reads are done:
    // the trailing __syncthreads above guarantees it).
    float* Lsum = (float*)As;          // [2][128]
    float* Lmax = Lsum + 256;          // [2][128]
    const int wi = w & 1;
    #pragma unroll
    for (int i = 0; i < 4; ++i) {
        #pragma unroll
        for (int r = 0; r < 4; ++r) {
            float rs = 0.f, rm = 0.f;
            #pragma unroll
            for (int j = 0; j < 4; ++j) {
                const float v = fmaxf(acc[i][j][r], 0.f);
                rs += v; rm = fmaxf(rm, v);
            }
            #pragma unroll
            for (int off = 1; off < 16; off <<= 1) {
                rs += __shfl_xor(rs, off);
                rm = fmaxf(rm, __shfl_xor(rm, off));
            }
            if (l15 == 0) {
                const int lr = rb + 16 * i + q * 4 + r;
                Lsum[wi * 128 + lr] = rs;
                Lmax[wi * 128 + lr] = rm;
            }
        }
    }
    __syncthreads();
    if (t < 128) {
        const int R = m0 + t;
        const int b = nt >> 5, chunk = nt & 31;
        const size_t o = (((size_t)s * MP + R) * Bn + b) * 32 + chunk;
        Psum[o] = Lsum[t] + Lsum[128 + t];
        Pmax[o] = fmaxf(Lmax[t], Lmax[128 + t]);
    }
}

// ---------------------------------------------------------------------------
// K4: tiny attention per (idx,b): reduce partials -> f,g,h -> softmax -> vout
// -> o = sigmoid(W_rec vout) -> coefA/coefK accumulation (fp32)
// ---------------------------------------------------------------------------
__global__ __launch_bounds__(256) void attn_small(
    const float* __restrict__ Psum, const float* __restrict__ Pmax,
    const float* __restrict__ Wrec,
    float* __restrict__ coefA, float* __restrict__ coefK)
{
    const int idx = blockIdx.x / Bn;
    const int bb  = blockIdx.x % Bn;
    __shared__ float ff[CPn], gg[CPn], hh[CPn], vout[CPn];
    const int t = threadIdx.x;

    if (t < CPn) {
        float v[3];
        #pragma unroll
        for (int tt = 0; tt < 3; ++tt) {
            const int s_ = (tt == 1) ? idx / 3 : idx % 3;
            const int m3 = (tt == 1) ? idx % 3 : idx / 3;
            const int R  = tt * 192 + m3 * 64 + t;
            const size_t base = (((size_t)s_ * MP + R) * Bn + bb) * 32;
            float sm = 0.f, mx = 0.f;
            #pragma unroll
            for (int u = 0; u < 32; ++u) {
                sm += Psum[base + u];
                mx = fmaxf(mx, Pmax[base + u]);
            }
            v[tt] = sm * (1.0f / HWn) + mx;
        }
        gg[t] = v[0];   // Q-pool
        ff[t] = v[1];   // K-pool
        hh[t] = v[2];   // V-pool
    }
    __syncthreads();

    if (t < CPn) {
        const float gj = gg[t];
        float mx = -1e30f;
        for (int i = 0; i < CPn; ++i) mx = fmaxf(mx, ff[i] * gj);
        float den = 0.f, num = 0.f;
        for (int i = 0; i < CPn; ++i) {
            const float e = expf(ff[i] * gj - mx);
            den += e;
            num += hh[i] * e;
        }
        vout[t] = num / den;
    }
    __syncthreads();

    {
        const float* wr = Wrec + ((size_t)idx * Cn + t) * CPn;
        float a = 0.f;
        for (int e = 0; e < CPn; ++e) a += vout[e] * wr[e];
        const float o = 1.0f / (1.0f + expf(-a));
        const int sj = idx % 3;
        const int si = idx / 3;
        atomicAdd(coefA + (sj * Bn + bb) * Cn + t, o);
        atomicAdd(coefK + (si * Bn + bb) * Cn + t, o);
    }
}

// ---------------------------------------------------------------------------
// K5: build composed output matrix Mm[b][m][s*256+c] bf16
// ---------------------------------------------------------------------------
__global__ __launch_bounds__(256) void build_M(
    const float* __restrict__ Wqkv,
    const float* __restrict__ coefA, const float* __restrict__ coefK,
    u16* __restrict__ Mm)
{
    const int s = blockIdx.x >> 8, m = blockIdx.x & 255;
    const int b = blockIdx.y;
    const int t = threadIdx.x;
    const float cA = coefA[(s * Bn + b) * Cn + m];
    const float cK = coefK[(s * Bn + b) * Cn + m];
    const float wq = Wqkv[((size_t)(3 * s + 0) * Cn + m) * Cn + t];
    const float wk = Wqkv[((size_t)(3 * s + 1) * Cn + m) * Cn + t];
    const float wv = Wqkv[((size_t)(3 * s + 2) * Cn + m) * Cn + t];
    Mm[((size_t)(b * 256 + m)) * 768 + s * 256 + t] = f2bf(cA * (wq + wv) + cK * wk);
}

// ---------------------------------------------------------------------------
// K6: out[b] (256 x 4096) = Mm[b] (256 x 768) @ xcat[b]^T.
// Tile 128(M) x 128(N), BK=128 -> 6 K-iters, 64 KB LDS, pane-ordered.
// Grid 2 x 32 x Bn = 256 blocks.
// ---------------------------------------------------------------------------
__global__ __launch_bounds__(256, 2) void final_mfma(
    const u16* __restrict__ xT, const u16* __restrict__ Mm,
    float* __restrict__ out)
{
    const int b  = blockIdx.y;
    const int mt = blockIdx.x >> 5, nt = blockIdx.x & 31;
    const int m0 = mt * 128, n0 = nt * 128;

    __shared__ __align__(16) u16 As[32 * 512];
    __shared__ __align__(16) u16 Bs[32 * 512];

    const int t = threadIdx.x;
    const int w = t >> 6, lane = t & 63;
    const int l15 = lane & 15, q = lane >> 4;
    const int rb = (w >> 1) * 64, cb = (w & 1) * 64;

    const u16* Apb = Mm + (size_t)(b * 256 + m0) * 768;

    floatx4 acc[4][4] = {};

    for (int k0 = 0; k0 < 768; k0 += 128) {
        const int s = k0 >> 8, c0 = k0 & 255;
        const u16* Asrc = Apb + (size_t)l15 * 768 + k0 + q * 8;
        const u16* Bsrc = xT + ((size_t)((s * Bn + b) * HWn) + n0 + l15) * Cn + c0 + q * 8;
        #pragma unroll
        for (int pi = 0; pi < 8; ++pi) {
            const int p = w * 8 + pi;
            const size_t roff = (size_t)((p >> 2) * 16);
            gld16(Asrc + roff * 768 + (p & 3) * 32, &As[p * 512]);
            gld16(Bsrc + roff * Cn + (p & 3) * 32, &Bs[p * 512]);
        }
        __syncthreads();
        #pragma unroll
        for (int kk = 0; kk < 4; ++kk) {
            short8 af[4], bf[4];
            #pragma unroll
            for (int i = 0; i < 4; ++i)
                af[i] = *(const short8*)&As[((((w >> 1) * 4 + i) << 2) + kk) * 512 + lane * 8];
            #pragma unroll
            for (int j = 0; j < 4; ++j)
                bf[j] = *(const short8*)&Bs[((((w & 1) * 4 + j) << 2) + kk) * 512 + lane * 8];
            #pragma unroll
            for (int i = 0; i < 4; ++i)
                #pragma unroll
                for (int j = 0; j < 4; ++j)
                    acc[i][j] = __builtin_amdgcn_mfma_f32_16x16x32_bf16(af[i], bf[j], acc[i][j], 0, 0, 0);
        }
        __syncthreads();
    }

    #pragma unroll
    for (int i = 0; i < 4; ++i)
        #pragma unroll
        for (int j = 0; j < 4; ++j)
            #pragma unroll
            for (int r = 0; r < 4; ++r) {
                const int row = m0 + rb + i * 16 + q * 4 + r;
                const int col = n0 + cb + j * 16 + l15;
                out[((size_t)(b * 256) + row) * HWn + col] = acc[i][j][r];
            }
}

extern "C" void kernel_launch(void* const* d_in, const int* in_sizes, int n_in,
                              void* d_out, int out_size, void* d_ws, size_t ws_size,
                              hipStream_t stream)
{
    const float* Tt   = (const float*)d_in[0];
    const float* Bt   = (const float*)d_in[1];
    const float* Mt   = (const float*)d_in[2];
    const float* Wqkv = (const float*)d_in[3];
    const float* Wred = (const float*)d_in[4];
    const float* Wrec = (const float*)d_in[5];
    float* out = (float*)d_out;

    unsigned char* p = (unsigned char*)d_ws;
    u16* xT = (u16*)p;            p += (size_t)3 * Bn * HWn * Cn * 2;   // 25.2 MB
    u16* Mm = (u16*)p;            p += (size_t)Bn * 256 * 768 * 2;      // 1.57 MB
    float* Psum = (float*)p;      p += (size_t)3 * MP * Bn * 32 * 4;    // 983 KB
    float* Pmax = (float*)p;      p += (size_t)3 * MP * Bn * 32 * 4;    // 983 KB
    unsigned char* zbase = p;
    u16* CWp = (u16*)p;           p += (size_t)3 * MP * Cn * 2;         // 983 KB (pad rows need 0)
    float* coefA = (float*)p;     p += (size_t)3 * Bn * Cn * 4;
    float* coefK = (float*)p;     p += (size_t)3 * Bn * Cn * 4;
    const size_t zbytes = (size_t)(p - zbase);

    hipMemsetAsync(zbase, 0, zbytes, stream);

    compose_red      <<<dim3(4, 9, 3),    256, 0, stream>>>(Wqkv, Wred, CWp);
    convert_transpose<<<dim3(256, Bn, 3), 256, 0, stream>>>(Tt, Bt, Mt, xT);
    redpool_mfma     <<<dim3(640, 1, 3),  256, 0, stream>>>(xT, CWp, Psum, Pmax);
    attn_small       <<<9 * Bn,           256, 0, stream>>>(Psum, Pmax, Wrec, coefA, coefK);
    build_M          <<<dim3(768, Bn),    256, 0, stream>>>(Wqkv, coefA, coefK, Mm);
    final_mfma       <<<dim3(64, Bn),     256, 0, stream>>>(xT, Mm, out);
}

// Round 7
// 170.301 us; speedup vs baseline: 1.2364x; 1.1627x over previous
//
#include <hip/hip_runtime.h>

#define Bn 4
#define Cn 256
#define HWn 4096
#define CPn 64
#define MP 640   // CW rows padded 576 -> 640 (5 x 128)

typedef unsigned short u16;
typedef unsigned int u32;

using short8  = __attribute__((ext_vector_type(8))) short;
using floatx4 = __attribute__((ext_vector_type(4))) float;

static __device__ __forceinline__ u16 f2bf(float f) {
    union { float f; u32 u; } v; v.f = f;
    u32 r = (v.u + 0x7FFFu + ((v.u >> 16) & 1u)) >> 16;
    return (u16)r;
}

// async global -> LDS, 16 B per lane. LDS dest = wave-uniform base + lane*16.
static __device__ __forceinline__ void gld16(const u16* g, u16* l) {
    __builtin_amdgcn_global_load_lds(
        (const __attribute__((address_space(1))) u32*)g,
        (__attribute__((address_space(3))) u32*)l, 16, 0, 0);
}

// Pane: 64 lanes x 16B = 1 KB; lane l = (row l&15, k-quad l>>4).
// Fragment read = base + lane*16B: contiguous, bank-conflict-free.

// ---------------------------------------------------------------------------
// K1: prep.  z<3: fp32 (C x HW) -> bf16 (HW x C) transpose (s=z).
//            z==3: compose CWp[s](640x256) = stack of Wred[idx] @ Wqkv[3s+tt].
// ---------------------------------------------------------------------------
__global__ __launch_bounds__(256) void prep(
    const float* __restrict__ Tt, const float* __restrict__ Bt, const float* __restrict__ Mt,
    const float* __restrict__ Wqkv, const float* __restrict__ Wred,
    u16* __restrict__ xT, u16* __restrict__ CWp)
{
    __shared__ u16 T[64][72];
    __shared__ float As[16][64];
    __shared__ float Bs[16][64];
    const int t = threadIdx.x;

    if (blockIdx.z < 3) {
        const int s  = blockIdx.z, b = blockIdx.y;
        const int ct = blockIdx.x & 3, hwt = blockIdx.x >> 2;
        const int c0 = ct * 64, hw0 = hwt * 64;
        const float* X = (s == 0 ? Tt : (s == 1 ? Bt : Mt)) + (size_t)b * Cn * HWn;

        const int cl = t >> 2, q = t & 3;
        const float* src = X + (size_t)(c0 + cl) * HWn + hw0 + q * 16;
        #pragma unroll
        for (int u = 0; u < 4; ++u) {
            const float4 v = *(const float4*)(src + u * 4);
            T[cl][q * 16 + u * 4 + 0] = f2bf(v.x);
            T[cl][q * 16 + u * 4 + 1] = f2bf(v.y);
            T[cl][q * 16 + u * 4 + 2] = f2bf(v.z);
            T[cl][q * 16 + u * 4 + 3] = f2bf(v.w);
        }
        __syncthreads();

        const int wl = t >> 2;
        u16* dst = xT + ((size_t)((s * Bn + b) * HWn) + hw0 + wl) * Cn + c0 + q * 16;
        #pragma unroll
        for (int u = 0; u < 2; ++u) {
            u32 w0 = (u32)T[q * 16 + u * 8 + 0][wl] | ((u32)T[q * 16 + u * 8 + 1][wl] << 16);
            u32 w1 = (u32)T[q * 16 + u * 8 + 2][wl] | ((u32)T[q * 16 + u * 8 + 3][wl] << 16);
            u32 w2 = (u32)T[q * 16 + u * 8 + 4][wl] | ((u32)T[q * 16 + u * 8 + 5][wl] << 16);
            u32 w3 = (u32)T[q * 16 + u * 8 + 6][wl] | ((u32)T[q * 16 + u * 8 + 7][wl] << 16);
            uint4 pk = {w0, w1, w2, w3};
            *(uint4*)(dst + u * 8) = pk;
        }
        return;
    }

    // compose branch: 108 real blocks out of (256,4) slot
    const int lin = blockIdx.y * 256 + blockIdx.x;
    if (lin >= 108) return;
    const int c0  = (lin & 3) * 64;
    const int rest = lin >> 2;           // 0..26
    const int y9 = rest % 9, s = rest / 9;
    const int tt = y9 / 3, m3 = y9 % 3;
    const int idx = (tt == 1) ? (3 * s + m3) : (3 * m3 + s);

    const float* A  = Wred + (size_t)idx * CPn * Cn;
    const float* Bm = Wqkv + (size_t)(3 * s + tt) * Cn * Cn;

    const int ty = t >> 4, tx = t & 15;
    float acc[4][4] = {};

    for (int k0 = 0; k0 < Cn; k0 += 16) {
        {
            const int r = t >> 2, eq = (t & 3) * 4;
            const float4 a = *(const float4*)(A + (size_t)r * Cn + k0 + eq);
            As[eq + 0][r] = a.x; As[eq + 1][r] = a.y; As[eq + 2][r] = a.z; As[eq + 3][r] = a.w;
        }
        {
            const int r = t >> 4, cq = (t & 15) * 4;
            *(float4*)(&Bs[r][cq]) = *(const float4*)(Bm + (size_t)(k0 + r) * Cn + c0 + cq);
        }
        __syncthreads();
        #pragma unroll
        for (int k = 0; k < 16; ++k) {
            const float4 a4 = *(const float4*)(&As[k][ty * 4]);
            const float4 b4 = *(const float4*)(&Bs[k][tx * 4]);
            const float a[4] = {a4.x, a4.y, a4.z, a4.w};
            const float bb[4] = {b4.x, b4.y, b4.z, b4.w};
            #pragma unroll
            for (int i = 0; i < 4; ++i)
                #pragma unroll
                for (int j = 0; j < 4; ++j)
                    acc[i][j] = fmaf(a[i], bb[j], acc[i][j]);
        }
        __syncthreads();
    }

    u16* outp = CWp + (size_t)s * MP * Cn;
    #pragma unroll
    for (int i = 0; i < 4; ++i) {
        const int row = tt * 192 + m3 * 64 + ty * 4 + i;
        unsigned long long pk =
            (unsigned long long)f2bf(acc[i][0]) |
            ((unsigned long long)f2bf(acc[i][1]) << 16) |
            ((unsigned long long)f2bf(acc[i][2]) << 32) |
            ((unsigned long long)f2bf(acc[i][3]) << 48);
        *(unsigned long long*)(outp + (size_t)row * Cn + c0 + tx * 4) = pk;
    }
}

// ---------------------------------------------------------------------------
// K2: persistent redpool.  Grid 240 = 5 mt x 16 nch x 3 s.  Block: A-tile
// (128 x 256) in VGPRs; loop 16 n-subtiles (64 cols), B dbuf in LDS with
// prefetch-after-barrier; relu+pool accumulated in registers; one partial
// store per row at the end.  Psum/Pmax[s][R][nch].
// ---------------------------------------------------------------------------
#define NSUB 16

__global__ __launch_bounds__(256, 1) void redpool_mfma(
    const u16* __restrict__ xT, const u16* __restrict__ CWp,
    float* __restrict__ Psum, float* __restrict__ Pmax)
{
    const int s   = blockIdx.z;
    const int mt  = blockIdx.x >> 4, nch = blockIdx.x & 15;
    const int m0  = mt * 128;
    const int nbase = nch * 1024;          // 16 subtiles x 64 cols, same b

    const u16* Ap = CWp + (size_t)s * MP * Cn;
    const u16* Bp = xT + (size_t)s * Bn * HWn * Cn;

    __shared__ __align__(16) u16 Bs[2][32 * 512];   // 2 x 32 KB

    const int t = threadIdx.x;
    const int w = t >> 6, lane = t & 63;
    const int l15 = lane & 15, q = lane >> 4;
    const int wr = w >> 1, wc = w & 1;     // wave: rows wr*64.., cols wc*32..

    // ---- A fragments: 4 row-blocks x 8 k-chunks, in registers ----
    short8 af[4][8];
    {
        const u16* Arow = Ap + (size_t)(m0 + wr * 64 + l15) * Cn + q * 8;
        #pragma unroll
        for (int i = 0; i < 4; ++i)
            #pragma unroll
            for (int kk = 0; kk < 8; ++kk)
                af[i][kk] = *(const short8*)(Arow + (size_t)(i * 16) * Cn + kk * 32);
    }

    // ---- B staging: 32 panes (4 col-blocks x 8 k-chunks) ----
    auto stageB = [&](int it, int buf) {
        const u16* Bsrc = Bp + (size_t)(nbase + it * 64 + l15) * Cn + q * 8;
        #pragma unroll
        for (int pi = 0; pi < 8; ++pi) {
            const int p = w * 8 + pi;
            gld16(Bsrc + (size_t)((p >> 3) * 16) * Cn + (p & 7) * 32, &Bs[buf][p * 512]);
        }
    };
    stageB(0, 0);

    float rs[4][4] = {};
    float rm[4][4] = {};

    for (int it = 0; it < NSUB; ++it) {
        __syncthreads();                       // drains B[it]; prev compute done
        if (it + 1 < NSUB) stageB(it + 1, (it + 1) & 1);   // overlapped prefetch
        const u16* bb = Bs[it & 1];

        floatx4 acc[4][2] = {};
        #pragma unroll
        for (int kk = 0; kk < 8; ++kk) {
            short8 bf[2];
            #pragma unroll
            for (int j = 0; j < 2; ++j)
                bf[j] = *(const short8*)&bb[((wc * 2 + j) * 8 + kk) * 512 + lane * 8];
            #pragma unroll
            for (int i = 0; i < 4; ++i)
                #pragma unroll
                for (int j = 0; j < 2; ++j)
                    acc[i][j] = __builtin_amdgcn_mfma_f32_16x16x32_bf16(af[i][kk], bf[j], acc[i][j], 0, 0, 0);
        }
        #pragma unroll
        for (int i = 0; i < 4; ++i)
            #pragma unroll
            for (int r = 0; r < 4; ++r) {
                const float v0 = fmaxf(acc[i][0][r], 0.f);
                const float v1 = fmaxf(acc[i][1][r], 0.f);
                rs[i][r] += v0 + v1;
                rm[i][r] = fmaxf(rm[i][r], fmaxf(v0, v1));
            }
    }

    // reduce over the 16 cols within the wave's half-tile
    #pragma unroll
    for (int i = 0; i < 4; ++i)
        #pragma unroll
        for (int r = 0; r < 4; ++r) {
            #pragma unroll
            for (int off = 1; off < 16; off <<= 1) {
                rs[i][r] += __shfl_xor(rs[i][r], off);
                rm[i][r] = fmaxf(rm[i][r], __shfl_xor(rm[i][r], off));
            }
        }

    // cross-wave combine (two col-half waves per row range) via LDS overlay
    __syncthreads();
    float* Lsum = (float*)&Bs[0][0];       // [2][128]
    float* Lmax = Lsum + 256;
    if (l15 == 0) {
        #pragma unroll
        for (int i = 0; i < 4; ++i)
            #pragma unroll
            for (int r = 0; r < 4; ++r) {
                const int row = wr * 64 + i * 16 + q * 4 + r;
                Lsum[wc * 128 + row] = rs[i][r];
                Lmax[wc * 128 + row] = rm[i][r];
            }
    }
    __syncthreads();
    if (t < 128) {
        const int R = m0 + t;
        const size_t o = ((size_t)s * MP + R) * 16 + nch;
        Psum[o] = Lsum[t] + Lsum[128 + t];
        Pmax[o] = fmaxf(Lmax[t], Lmax[128 + t]);
    }
}

// ---------------------------------------------------------------------------
// K3: tiny attention per (idx,b): reduce 4 chunks -> f,g,h -> softmax -> vout.
// 64 threads (1 wave), 36 blocks.
// ---------------------------------------------------------------------------
__global__ __launch_bounds__(64) void attn_small(
    const float* __restrict__ Psum, const float* __restrict__ Pmax,
    float* __restrict__ vout)
{
    const int idx = blockIdx.x / Bn;
    const int bb  = blockIdx.x % Bn;
    __shared__ float ff[CPn], gg[CPn], hh[CPn];
    const int t = threadIdx.x;

    float v[3];
    #pragma unroll
    for (int tt = 0; tt < 3; ++tt) {
        const int s_ = (tt == 1) ? idx / 3 : idx % 3;
        const int m3 = (tt == 1) ? idx % 3 : idx / 3;
        const int R  = tt * 192 + m3 * 64 + t;
        const size_t base = ((size_t)s_ * MP + R) * 16 + bb * 4;
        float sm = 0.f, mx = 0.f;
        #pragma unroll
        for (int u = 0; u < 4; ++u) {
            sm += Psum[base + u];
            mx = fmaxf(mx, Pmax[base + u]);
        }
        v[tt] = sm * (1.0f / HWn) + mx;
    }
    gg[t] = v[0];   // Q-pool
    ff[t] = v[1];   // K-pool
    hh[t] = v[2];   // V-pool
    __syncthreads();

    const float gj = gg[t];
    float mx = -1e30f;
    for (int i = 0; i < CPn; ++i) mx = fmaxf(mx, ff[i] * gj);
    float den = 0.f, num = 0.f;
    for (int i = 0; i < CPn; ++i) {
        const float e = expf(ff[i] * gj - mx);
        den += e;
        num += hh[i] * e;
    }
    vout[((size_t)idx * Bn + bb) * CPn + t] = num / den;
}

// ---------------------------------------------------------------------------
// K4: build Mm[b][m][s*256+c] bf16, computing coefs inline from vout:
//   cA = sum_{j} sigmoid(vout[s+3j,b] . Wrec[s+3j][m]),  cK over idx=3s+j.
// ---------------------------------------------------------------------------
__global__ __launch_bounds__(256) void build_M(
    const float* __restrict__ Wqkv, const float* __restrict__ Wrec,
    const float* __restrict__ vout, u16* __restrict__ Mm)
{
    const int s = blockIdx.x >> 8, m = blockIdx.x & 255;
    const int b = blockIdx.y;
    const int t = threadIdx.x;
    __shared__ float cc[2];

    if (t < CPn) {
        float d[6];
        #pragma unroll
        for (int j = 0; j < 6; ++j) {
            const int idx = (j < 3) ? (s + 3 * j) : (3 * s + (j - 3));
            d[j] = vout[((size_t)idx * Bn + b) * CPn + t] *
                   Wrec[((size_t)idx * Cn + m) * CPn + t];
        }
        #pragma unroll
        for (int off = 32; off >= 1; off >>= 1)
            #pragma unroll
            for (int j = 0; j < 6; ++j)
                d[j] += __shfl_xor(d[j], off);
        if (t == 0) {
            float cA = 0.f, cK = 0.f;
            #pragma unroll
            for (int j = 0; j < 3; ++j) {
                cA += 1.0f / (1.0f + expf(-d[j]));
                cK += 1.0f / (1.0f + expf(-d[j + 3]));
            }
            cc[0] = cA; cc[1] = cK;
        }
    }
    __syncthreads();
    const float cA = cc[0], cK = cc[1];
    const float wq = Wqkv[((size_t)(3 * s + 0) * Cn + m) * Cn + t];
    const float wk = Wqkv[((size_t)(3 * s + 1) * Cn + m) * Cn + t];
    const float wv = Wqkv[((size_t)(3 * s + 2) * Cn + m) * Cn + t];
    Mm[((size_t)(b * 256 + m)) * 768 + s * 256 + t] = f2bf(cA * (wq + wv) + cK * wk);
}

// ---------------------------------------------------------------------------
// K5: out[b] (256 x 4096) = Mm[b] (256 x 768) @ xcat[b]^T.
// Tile 128x128, BK=128, 6 iters, A+B double-buffered (128 KB LDS),
// prefetch-after-barrier: one barrier per iter.  Grid 2 x 32 x Bn = 256.
// ---------------------------------------------------------------------------
__global__ __launch_bounds__(256, 1) void final_mfma(
    const u16* __restrict__ xT, const u16* __restrict__ Mm,
    float* __restrict__ out)
{
    const int b  = blockIdx.y;
    const int mt = blockIdx.x >> 5, nt = blockIdx.x & 31;
    const int m0 = mt * 128, n0 = nt * 128;

    __shared__ __align__(16) u16 As[2][32 * 512];
    __shared__ __align__(16) u16 Bs[2][32 * 512];

    const int t = threadIdx.x;
    const int w = t >> 6, lane = t & 63;
    const int l15 = lane & 15, q = lane >> 4;
    const int rb = (w >> 1) * 64, cb = (w & 1) * 64;

    auto stage = [&](int it, int buf) {
        const int k0 = it * 128;
        const int s = k0 >> 8, c0 = k0 & 255;
        const u16* Asrc = Mm + (size_t)(b * 256 + m0 + l15) * 768 + k0 + q * 8;
        const u16* Bsrc = xT + ((size_t)((s * Bn + b) * HWn) + n0 + l15) * Cn + c0 + q * 8;
        #pragma unroll
        for (int pi = 0; pi < 8; ++pi) {
            const int p = w * 8 + pi;
            const size_t roff = (size_t)((p >> 2) * 16);
            gld16(Asrc + roff * 768 + (p & 3) * 32, &As[buf][p * 512]);
            gld16(Bsrc + roff * Cn + (p & 3) * 32, &Bs[buf][p * 512]);
        }
    };
    stage(0, 0);

    floatx4 acc[4][4] = {};

    for (int it = 0; it < 6; ++it) {
        __syncthreads();
        if (it + 1 < 6) stage(it + 1, (it + 1) & 1);
        const u16* as = As[it & 1];
        const u16* bs = Bs[it & 1];
        #pragma unroll
        for (int kk = 0; kk < 4; ++kk) {
            short8 af[4], bf[4];
            #pragma unroll
            for (int i = 0; i < 4; ++i)
                af[i] = *(const short8*)&as[((((w >> 1) * 4 + i) << 2) + kk) * 512 + lane * 8];
            #pragma unroll
            for (int j = 0; j < 4; ++j)
                bf[j] = *(const short8*)&bs[((((w & 1) * 4 + j) << 2) + kk) * 512 + lane * 8];
            #pragma unroll
            for (int i = 0; i < 4; ++i)
                #pragma unroll
                for (int j = 0; j < 4; ++j)
                    acc[i][j] = __builtin_amdgcn_mfma_f32_16x16x32_bf16(af[i], bf[j], acc[i][j], 0, 0, 0);
        }
    }

    #pragma unroll
    for (int i = 0; i < 4; ++i)
        #pragma unroll
        for (int j = 0; j < 4; ++j)
            #pragma unroll
            for (int r = 0; r < 4; ++r) {
                const int row = m0 + rb + i * 16 + q * 4 + r;
                const int col = n0 + cb + j * 16 + l15;
                out[((size_t)(b * 256) + row) * HWn + col] = acc[i][j][r];
            }
}

extern "C" void kernel_launch(void* const* d_in, const int* in_sizes, int n_in,
                              void* d_out, int out_size, void* d_ws, size_t ws_size,
                              hipStream_t stream)
{
    const float* Tt   = (const float*)d_in[0];
    const float* Bt   = (const float*)d_in[1];
    const float* Mt   = (const float*)d_in[2];
    const float* Wqkv = (const float*)d_in[3];
    const float* Wred = (const float*)d_in[4];
    const float* Wrec = (const float*)d_in[5];
    float* out = (float*)d_out;

    unsigned char* p = (unsigned char*)d_ws;
    u16* xT = (u16*)p;            p += (size_t)3 * Bn * HWn * Cn * 2;   // 25.2 MB
    u16* Mm = (u16*)p;            p += (size_t)Bn * 256 * 768 * 2;      // 1.57 MB
    u16* CWp = (u16*)p;           p += (size_t)3 * MP * Cn * 2;         // 983 KB
    float* Psum = (float*)p;      p += (size_t)3 * MP * 16 * 4;         // 123 KB
    float* Pmax = (float*)p;      p += (size_t)3 * MP * 16 * 4;         // 123 KB
    float* vout = (float*)p;      p += (size_t)9 * Bn * CPn * 4;        // 9.2 KB

    prep        <<<dim3(256, Bn, 4), 256, 0, stream>>>(Tt, Bt, Mt, Wqkv, Wred, xT, CWp);
    redpool_mfma<<<dim3(80, 1, 3),   256, 0, stream>>>(xT, CWp, Psum, Pmax);
    attn_small  <<<9 * Bn,            64, 0, stream>>>(Psum, Pmax, vout);
    build_M     <<<dim3(768, Bn),    256, 0, stream>>>(Wqkv, Wrec, vout, Mm);
    final_mfma  <<<dim3(64, Bn),     256, 0, stream>>>(xT, Mm, out);
}